// Round 8
// baseline (3445.404 us; speedup 1.0000x reference)
//
#include <hip/hip_runtime.h>
#include <hip/hip_bf16.h>

#define DD 768
#define NPATCH 576
#define NPAD 640          // 40 patch tiles of 16
#define NPT 40
#define BMR 64            // mem rows per chunk
#define GRID 256
#define EPSF 1e-6f

typedef short bf16x8 __attribute__((ext_vector_type(8)));
typedef float f32x4 __attribute__((ext_vector_type(4)));

__device__ __forceinline__ unsigned short f2bf(float x) {
  __hip_bfloat16 h = __float2bfloat16(x);
  return __builtin_bit_cast(unsigned short, h);
}

__device__ __forceinline__ void gload_lds16(const float* g, char* lds) {
  __builtin_amdgcn_global_load_lds(
      (const __attribute__((address_space(1))) unsigned int*)(g),
      (__attribute__((address_space(3))) unsigned int*)(lds), 16, 0, 0);
}

// ---------------- kernel 1: patch row norms ----------------
__global__ __launch_bounds__(256) void k_norm(const float* __restrict__ pf,
                                              float* __restrict__ invn) {
  int row = blockIdx.x;          // 576
  int t = threadIdx.x;
  const float* src = pf + (size_t)row * DD;
  float v0 = src[t], v1 = src[t + 256], v2 = src[t + 512];
  float ss = v0 * v0 + v1 * v1 + v2 * v2;
#pragma unroll
  for (int m = 1; m < 64; m <<= 1) ss += __shfl_xor(ss, m, 64);
  __shared__ float wss[4];
  if ((t & 63) == 0) wss[t >> 6] = ss;
  __syncthreads();
  if (t == 0) {
    float tot = wss[0] + wss[1] + wss[2] + wss[3];
    invn[row] = 1.0f / (sqrtf(tot) + EPSF);
  }
}

// ---------------- kernel 2: pack F into slab-fragment layout ----------------
// Fws[ks32][ptg][slot][8] bf16: patch = ptg*16+(slot&15), k = ks32*32+(slot>>4)*8+j
__global__ __launch_bounds__(256) void k_pack(const float* __restrict__ pf,
                                              const float* __restrict__ invn,
                                              unsigned short* __restrict__ Fws) {
  int bid = blockIdx.x;          // 960 = 24 ks * 40 ptg
  int ks = bid / NPT, ptg = bid % NPT;
  int t = threadIdx.x;
  int i = t * 2;                 // short index in region [0,512)
  int s = i >> 3, j = i & 7;
  int p = ptg * 16 + (s & 15);
  int k = ks * 32 + (s >> 4) * 8 + j;
  unsigned int outw = 0;
  if (p < NPATCH) {
    float sc = invn[p];
    float a0 = pf[(size_t)p * DD + k] * sc;
    float a1 = pf[(size_t)p * DD + k + 1] * sc;
    outw = (unsigned int)f2bf(a0) | ((unsigned int)f2bf(a1) << 16);
  }
  ((unsigned int*)Fws)[(size_t)bid * 256 + t] = outw;
}

#define PACK_BW(bw, u0, u1)                                               \
  bw.x = (unsigned int)f2bf(u0.x) | ((unsigned int)f2bf(u0.y) << 16);     \
  bw.y = (unsigned int)f2bf(u0.z) | ((unsigned int)f2bf(u0.w) << 16);     \
  bw.z = (unsigned int)f2bf(u1.x) | ((unsigned int)f2bf(u1.y) << 16);     \
  bw.w = (unsigned int)f2bf(u1.z) | ((unsigned int)f2bf(u1.w) << 16);

#define SQ8(u0, u1)                                                        \
  (u0.x * u0.x + u0.y * u0.y + u0.z * u0.z + u0.w * u0.w +                 \
   u1.x * u1.x + u1.y * u1.y + u1.z * u1.z + u1.w * u1.w)

// Stage slab SL (0..11) of chunk CC into LDS buf SL%3 via global_load_lds.
// Source address pre-swizzled (16B slot ^ row&7) so frag ds_reads are ideal.
#define STAGE(SL, CC)                                                       \
  {                                                                         \
    int cc_ = (CC);                                                         \
    int gr0_ = cc_ * BMR + r0; if (gr0_ > M - 1) gr0_ = M - 1;              \
    int gr1_ = cc_ * BMR + r1; if (gr1_ > M - 1) gr1_ = M - 1;              \
    const float* g0_ = mem + (size_t)gr0_ * DD + (SL) * 64 + c0;            \
    const float* g1_ = mem + (size_t)gr1_ * DD + (SL) * 64 + c1;            \
    char* lb_ = (char*)Bs[(SL) % 3];                                        \
    gload_lds16(g0_, lb_ + w * 1024 + lx16);                                \
    gload_lds16(g1_, lb_ + 8192 + w * 1024 + lx16);                         \
  }

// One BK=64 step on slab S (buf S%3): issue A(kh0)+A(kh1), stage slab S+2,
// kh0: 8 ds_read_b128 -> vmcnt(7) [drains stage(S+1)+A0] -> cvt+20 MFMA,
// kh1: 8 ds_read_b128 -> vmcnt(2) [drains A1, leaves stage(S+2)] -> cvt+20 MFMA.
#define STEP(S, CCS)                                                         \
  {                                                                          \
    asm volatile("s_waitcnt vmcnt(2)" ::: "memory");                         \
    __builtin_amdgcn_sched_barrier(0);                                       \
    __builtin_amdgcn_s_barrier();                                            \
    __builtin_amdgcn_sched_barrier(0);                                       \
    const unsigned short* A0p_ = Abase + (size_t)(2 * (S)) * (NPT * 512);    \
    const unsigned short* A1p_ = A0p_ + (NPT * 512);                         \
    bf16x8 a0_[5], a1_[5];                                                   \
    _Pragma("unroll") for (int p = 0; p < 5; ++p)                            \
        a0_[p] = *(const bf16x8*)(A0p_ + p * 512);                           \
    _Pragma("unroll") for (int p = 0; p < 5; ++p)                            \
        a1_[p] = *(const bf16x8*)(A1p_ + p * 512);                           \
    __builtin_amdgcn_sched_barrier(0);                                       \
    STAGE(((S) + 2) % 12, CCS);                                              \
    __builtin_amdgcn_sched_barrier(0);                                       \
    const char* bp_ = (const char*)Bs[(S) % 3];                              \
    float4 lo_[4], hi_[4];                                                   \
    _Pragma("unroll") for (int rt = 0; rt < 4; ++rt) {                       \
      lo_[rt] = *(const float4*)(bp_ + rt * 4096 + rowbyte + so00);          \
      hi_[rt] = *(const float4*)(bp_ + rt * 4096 + rowbyte + so01);          \
    }                                                                        \
    asm volatile("s_waitcnt vmcnt(7)" ::: "memory");                         \
    asm volatile("s_waitcnt lgkmcnt(0)" ::: "memory");                       \
    __builtin_amdgcn_sched_barrier(0);                                       \
    bf16x8 b_[4];                                                            \
    _Pragma("unroll") for (int rt = 0; rt < 4; ++rt) {                       \
      uint4 bw_;                                                             \
      PACK_BW(bw_, lo_[rt], hi_[rt]);                                        \
      b_[rt] = __builtin_bit_cast(bf16x8, bw_);                              \
      ssqa[rt] += SQ8(lo_[rt], hi_[rt]);                                     \
    }                                                                        \
    __builtin_amdgcn_s_setprio(1);                                           \
    _Pragma("unroll") for (int p = 0; p < 5; ++p)                            \
      _Pragma("unroll") for (int rt = 0; rt < 4; ++rt)                       \
        acc[p][rt] = __builtin_amdgcn_mfma_f32_16x16x32_bf16(a0_[p], b_[rt], acc[p][rt], 0, 0, 0); \
    __builtin_amdgcn_s_setprio(0);                                           \
    __builtin_amdgcn_sched_barrier(0);                                       \
    _Pragma("unroll") for (int rt = 0; rt < 4; ++rt) {                       \
      lo_[rt] = *(const float4*)(bp_ + rt * 4096 + rowbyte + so10);          \
      hi_[rt] = *(const float4*)(bp_ + rt * 4096 + rowbyte + so11);          \
    }                                                                        \
    asm volatile("s_waitcnt vmcnt(2)" ::: "memory");                         \
    asm volatile("s_waitcnt lgkmcnt(0)" ::: "memory");                       \
    __builtin_amdgcn_sched_barrier(0);                                       \
    _Pragma("unroll") for (int rt = 0; rt < 4; ++rt) {                       \
      uint4 bw_;                                                             \
      PACK_BW(bw_, lo_[rt], hi_[rt]);                                        \
      b_[rt] = __builtin_bit_cast(bf16x8, bw_);                              \
      ssqa[rt] += SQ8(lo_[rt], hi_[rt]);                                     \
    }                                                                        \
    __builtin_amdgcn_s_setprio(1);                                           \
    _Pragma("unroll") for (int p = 0; p < 5; ++p)                            \
      _Pragma("unroll") for (int rt = 0; rt < 4; ++rt)                       \
        acc[p][rt] = __builtin_amdgcn_mfma_f32_16x16x32_bf16(a1_[p], b_[rt], acc[p][rt], 0, 0, 0); \
    __builtin_amdgcn_s_setprio(0);                                           \
    __builtin_amdgcn_sched_barrier(0);                                       \
  }

// ---------------- kernel 3: main MFMA kernel ----------------
// 512 threads = 8 waves; wave w owns patch tiles w*5..w*5+4, ALL 4 row-tiles.
// Each chunk (64 rows) is owned by exactly one block: B read once from HBM.
__global__ __launch_bounds__(512, 1) void k_main(const unsigned short* __restrict__ Fws,
                                                 const float* __restrict__ mem,
                                                 float* __restrict__ partial,
                                                 int M, int nchunk) {
  __shared__ __align__(16) float Bs[3][4096];   // 3 x 16KB fp32 slabs
  __shared__ float ssq[BMR];
  __shared__ float smin[NPAD];

  int t = threadIdx.x;
  int w = t >> 6, l = t & 63, l15 = l & 15, lhi = l >> 4;
  int lx16 = l * 16;
  // staging decode: issue j covers rows j*32 + w*4 + (l>>4), 16B slot l&15
  int r0 = w * 4 + (l >> 4);
  int r1 = 32 + r0;
  int c0 = (((l & 15) ^ (r0 & 7)) * 4);   // pre-swizzled source float offset
  int c1 = (((l & 15) ^ (r1 & 7)) * 4);
  // fragment-read swizzled 16B-slot offsets (slot ^ (row&7); row&7 == l15&7)
  int sw = l15 & 7;
  int rowbyte = l15 * 256;
  int so00 = ((lhi * 2) ^ sw) * 16;
  int so01 = ((lhi * 2 + 1) ^ sw) * 16;
  int so10 = so00 + 128;                  // (8+x)^sw == 8+(x^sw) for sw<8
  int so11 = so01 + 128;

  const unsigned short* Abase =
      Fws + (size_t)(w * 5) * 512 + (size_t)(lhi * 16 + l15) * 8;

  for (int i = t; i < NPAD; i += 512) smin[i] = 1e30f;

  int chunk = blockIdx.x;
  STAGE(0, chunk);
  STAGE(1, chunk);

#pragma unroll 1
  for (; chunk < nchunk; chunk += gridDim.x) {
    int cnx = chunk + gridDim.x;
    if (cnx >= nchunk) cnx = chunk;      // dummy (keeps vmcnt counts uniform)

    f32x4 acc[5][4];
#pragma unroll
    for (int p = 0; p < 5; ++p)
#pragma unroll
      for (int rt = 0; rt < 4; ++rt) {
        f32x4 z = {0.f, 0.f, 0.f, 0.f};
        acc[p][rt] = z;
      }
    float ssqa[4] = {0.f, 0.f, 0.f, 0.f};

    STEP(0, chunk)  STEP(1, chunk)  STEP(2, chunk)  STEP(3, chunk)
    STEP(4, chunk)  STEP(5, chunk)  STEP(6, chunk)  STEP(7, chunk)
    STEP(8, chunk)  STEP(9, chunk)  STEP(10, cnx)   STEP(11, cnx)

    // ---- epilogue: ssq publish, dist, per-patch min ----
#pragma unroll
    for (int rt = 0; rt < 4; ++rt) {
      float v = ssqa[rt];
      v += __shfl_xor(v, 16, 64);
      v += __shfl_xor(v, 32, 64);
      if (w == 0 && lhi == 0) ssq[rt * 16 + l15] = v;
    }
    asm volatile("s_waitcnt lgkmcnt(0)" ::: "memory");
    __builtin_amdgcn_sched_barrier(0);
    __builtin_amdgcn_s_barrier();
    float inv_[4];
#pragma unroll
    for (int rt = 0; rt < 4; ++rt)
      inv_[rt] = 1.0f / (sqrtf(ssq[rt * 16 + l15]) + EPSF);
#pragma unroll
    for (int p = 0; p < 5; ++p) {
#pragma unroll
      for (int q = 0; q < 4; ++q) {
        float d = 1.0f - acc[p][0][q] * inv_[0];
        d = fminf(d, 1.0f - acc[p][1][q] * inv_[1]);
        d = fminf(d, 1.0f - acc[p][2][q] * inv_[2]);
        d = fminf(d, 1.0f - acc[p][3][q] * inv_[3]);
        d = fminf(d, __shfl_xor(d, 1, 64));
        d = fminf(d, __shfl_xor(d, 2, 64));
        d = fminf(d, __shfl_xor(d, 4, 64));
        d = fminf(d, __shfl_xor(d, 8, 64));
        if (l15 == 0) {
          int pl = (w * 5 + p) * 16 + lhi * 4 + q;
          smin[pl] = fminf(smin[pl], d);
        }
      }
    }
  }

  __builtin_amdgcn_s_barrier();
  for (int i = t; i < NPATCH; i += 512)
    partial[(size_t)blockIdx.x * NPAD + i] = smin[i];
}

// ---------------- kernel 4: min over partials -> patch_scores ----------------
__global__ __launch_bounds__(256) void k_colmin(const float* __restrict__ partial,
                                                float* __restrict__ out, int nb) {
  int p = blockIdx.x;   // 576
  int t = threadIdx.x;
  float v = 1e30f;
  for (int b = t; b < nb; b += 256) v = fminf(v, partial[(size_t)b * NPAD + p]);
#pragma unroll
  for (int m = 1; m < 64; m <<= 1) v = fminf(v, __shfl_xor(v, m, 64));
  __shared__ float wmin[4];
  if ((t & 63) == 0) wmin[t >> 6] = v;
  __syncthreads();
  if (t == 0) out[p] = fminf(fminf(wmin[0], wmin[1]), fminf(wmin[2], wmin[3]));
}

// ---------------- kernel 5: top-k mean -> image score ----------------
__global__ __launch_bounds__(256) void k_topk(float* __restrict__ out,
                                              const int* __restrict__ topk_p) {
  __shared__ float vals[NPATCH];
  __shared__ float wv[4];
  __shared__ int wi[4];
  __shared__ float ssum;
  int t = threadIdx.x;
  for (int p = t; p < NPATCH; p += 256) vals[p] = out[p];
  if (t == 0) ssum = 0.f;
  int k = topk_p[0];
  if (k > NPATCH) k = NPATCH;
  if (k < 1) k = 1;
  __syncthreads();
  for (int it = 0; it < k; ++it) {
    float bv = -1e30f;
    int bi = 0;
    for (int p = t; p < NPATCH; p += 256) {
      float x = vals[p];
      if (x > bv) { bv = x; bi = p; }
    }
#pragma unroll
    for (int m = 1; m < 64; m <<= 1) {
      float ov = __shfl_xor(bv, m, 64);
      int oi = __shfl_xor(bi, m, 64);
      if (ov > bv || (ov == bv && oi < bi)) { bv = ov; bi = oi; }
    }
    if ((t & 63) == 0) { wv[t >> 6] = bv; wi[t >> 6] = bi; }
    __syncthreads();
    if (t == 0) {
      float fbv = wv[0]; int fbi = wi[0];
      for (int q = 1; q < 4; ++q)
        if (wv[q] > fbv || (wv[q] == fbv && wi[q] < fbi)) { fbv = wv[q]; fbi = wi[q]; }
      ssum += fbv;
      vals[fbi] = -1e30f;
    }
    __syncthreads();
  }
  if (t == 0) out[NPATCH] = ssum / (float)k;
}

extern "C" void kernel_launch(void* const* d_in, const int* in_sizes, int n_in,
                              void* d_out, int out_size, void* d_ws, size_t ws_size,
                              hipStream_t stream) {
  const float* pf = (const float*)d_in[0];
  const float* mem = (const float*)d_in[1];
  const int* topk = (const int*)d_in[2];
  float* out = (float*)d_out;
  int M = in_sizes[1] / DD;                      // 200000
  int nchunk = (M + BMR - 1) / BMR;              // 3125

  // ws: Fws (24*40*512 shorts = 983040B) | invn (2304B) | partial (256*640*4)
  unsigned short* Fws = (unsigned short*)d_ws;
  float* invn = (float*)((char*)d_ws + 983040);
  float* partial = (float*)((char*)d_ws + 983040 + 2304);

  int grid = GRID;
  if (grid > nchunk) grid = nchunk;

  k_norm<<<NPATCH, 256, 0, stream>>>(pf, invn);
  k_pack<<<24 * NPT, 256, 0, stream>>>(pf, invn, Fws);
  k_main<<<grid, 512, 0, stream>>>(Fws, mem, partial, M, nchunk);
  k_colmin<<<NPATCH, 256, 0, stream>>>(partial, out, grid);
  k_topk<<<1, 256, 0, stream>>>(out, topk);
}

// Round 9
// 506.266 us; speedup vs baseline: 6.8055x; 6.8055x over previous
//
#include <hip/hip_runtime.h>
#include <hip/hip_bf16.h>

#define DD 768
#define NPATCH 576
#define BMR 64            // mem rows per chunk
#define NSLAB 24          // K slabs of 32
#define EPSF 1e-6f
#define NRB 384           // row-block groups; grid = 2 * NRB = 768 = 3 blocks/CU

typedef short bf16x8 __attribute__((ext_vector_type(8)));
typedef float f32x4 __attribute__((ext_vector_type(4)));

__device__ __forceinline__ unsigned short f2bf(float x) {
  __hip_bfloat16 h = __float2bfloat16(x);
  return __builtin_bit_cast(unsigned short, h);
}

// ---------------- kernel 1: patch row norms ----------------
__global__ __launch_bounds__(256) void k_norm(const float* __restrict__ pf,
                                              float* __restrict__ invn) {
  int row = blockIdx.x;          // 576
  int t = threadIdx.x;
  const float* src = pf + (size_t)row * DD;
  float v0 = src[t], v1 = src[t + 256], v2 = src[t + 512];
  float ss = v0 * v0 + v1 * v1 + v2 * v2;
#pragma unroll
  for (int m = 1; m < 64; m <<= 1) ss += __shfl_xor(ss, m, 64);
  __shared__ float wss[4];
  if ((t & 63) == 0) wss[t >> 6] = ss;
  __syncthreads();
  if (t == 0) {
    float tot = wss[0] + wss[1] + wss[2] + wss[3];
    invn[row] = 1.0f / (sqrtf(tot) + EPSF);
  }
}

// ---------------- kernel 2: pack F into slab-fragment layout ----------------
// Fws[ks][ptg][slot][8] bf16: patch = ptg*16 + (slot&15), k = ks*32 + (slot>>4)*8 + j
__global__ __launch_bounds__(256) void k_pack(const float* __restrict__ pf,
                                              const float* __restrict__ invn,
                                              unsigned short* __restrict__ Fws) {
  int bid = blockIdx.x;          // 864 = 24 ks * 36 ptg
  int ks = bid / 36, ptg = bid % 36;
  int t = threadIdx.x;
  int i = t * 2;                 // short index in region [0,512)
  int s = i >> 3, j = i & 7;
  int p = ptg * 16 + (s & 15);
  int k = ks * 32 + (s >> 4) * 8 + j;
  float sc = invn[p];
  float a0 = pf[(size_t)p * DD + k] * sc;
  float a1 = pf[(size_t)p * DD + k + 1] * sc;
  unsigned int outw = (unsigned int)f2bf(a0) | ((unsigned int)f2bf(a1) << 16);
  ((unsigned int*)Fws)[(size_t)bid * 256 + t] = outw;
}

// pack two float4 (8 fp32) into a uint4 of 8 bf16
#define PACK_BW(bw, u0, u1)                                               \
  bw.x = (unsigned int)f2bf(u0.x) | ((unsigned int)f2bf(u0.y) << 16);     \
  bw.y = (unsigned int)f2bf(u0.z) | ((unsigned int)f2bf(u0.w) << 16);     \
  bw.z = (unsigned int)f2bf(u1.x) | ((unsigned int)f2bf(u1.y) << 16);     \
  bw.w = (unsigned int)f2bf(u1.z) | ((unsigned int)f2bf(u1.w) << 16);

#define SQ8(u0, u1)                                                        \
  (u0.x * u0.x + u0.y * u0.y + u0.z * u0.z + u0.w * u0.w +                 \
   u1.x * u1.x + u1.y * u1.y + u1.z * u1.z + u1.w * u1.w)

// One K-slab step n:
//   load A(n) fragments (L2-hot, partially hidden by convert phase);
//   issue B(n+3) -> I (2-step flight >= HBM latency before its convert);
//   convert C=B(n+1) -> Bs[buf^1]; ds_read b from Bs[buf]; 18 MFMA.
// Compiler-managed waits (proven R5 discipline).
#define KSTEP(n, buf, C0, C1, I0, I1)                                      \
  {                                                                        \
    const unsigned short* Ak = Abase + (size_t)(n) * (36 * 512);           \
    bf16x8 ar[9];                                                          \
    _Pragma("unroll")                                                      \
    for (int p = 0; p < 9; ++p) ar[p] = *(const bf16x8*)(Ak + p * 512);    \
    __builtin_amdgcn_sched_barrier(0); /* keep B issue AFTER A issue */    \
    if ((n) + 3 < NSLAB) {                                                 \
      const float* g = gsrc + ((n) + 3) * 32;                              \
      I0 = *(const float4*)g;                                              \
      I1 = *(const float4*)(g + 4);                                        \
    }                                                                      \
    __builtin_amdgcn_sched_barrier(0);                                     \
    if ((n) < NSLAB - 1) {                                                 \
      ssr += SQ8(C0, C1);                                                  \
      uint4 bw;                                                            \
      PACK_BW(bw, C0, C1);                                                 \
      *(uint4*)((char*)Bs[(buf) ^ 1] + wbyte) = bw;                        \
    }                                                                      \
    __builtin_amdgcn_sched_barrier(0);                                     \
    bf16x8 b0 = *(const bf16x8*)((const char*)Bs[buf] + rbyte0);           \
    bf16x8 b1 = *(const bf16x8*)((const char*)Bs[buf] + rbyte1);           \
    asm volatile("s_waitcnt lgkmcnt(0)" ::: "memory");                     \
    __builtin_amdgcn_sched_barrier(0);                                     \
    _Pragma("unroll")                                                      \
    for (int p = 0; p < 9; ++p) {                                          \
      acc[p][0] = __builtin_amdgcn_mfma_f32_16x16x32_bf16(ar[p], b0, acc[p][0], 0, 0, 0); \
      acc[p][1] = __builtin_amdgcn_mfma_f32_16x16x32_bf16(ar[p], b1, acc[p][1], 0, 0, 0); \
    }                                                                      \
    __builtin_amdgcn_sched_barrier(0);                                     \
    __builtin_amdgcn_s_barrier();                                          \
  }

// ---------------- kernel 3: main MFMA kernel ----------------
// 256 threads = 4 waves: pw = w&1 (9 patch-tiles each), rw = w>>1 (2 row-tiles each)
// A inline from L2-resident Fws; B reg-prefetch depth 4 (sets P,Q,R,T) -> LDS dbuf.
// Grid 768 = 3 blocks/CU: inter-block overlap hides per-step barrier/latency stalls.
__global__ __launch_bounds__(256, 3) void k_main(const unsigned short* __restrict__ Fws,
                                                 const float* __restrict__ mem,
                                                 float* __restrict__ partial,
                                                 int M, int nchunk) {
  __shared__ __align__(16) unsigned short Bs[2][2048];   // 2 x 4KB bf16 slab
  __shared__ float smin[2][288];
  __shared__ float ssq[BMR];

  int t = threadIdx.x;
  int l = t & 63, l15 = l & 15, lhi = l >> 4;
  int w = t >> 6, pw = w & 1, rw = w >> 1;
  int c = blockIdx.x & 1, rb = blockIdx.x >> 1;
  int srow = t >> 2, sq = t & 3;      // staging: row 0..63, k-seg 0..3

  for (int i = t; i < 2 * 288; i += 256) ((float*)smin)[i] = 1e30f;

  const unsigned short* Abase =
      Fws + (size_t)(c * 18 + pw * 9) * 512 + (size_t)(lhi * 16 + l15) * 8;

  int rbyte0, rbyte1;
  {
    int sw = ((l15 & 7) << 4);
    rbyte0 = (rw * 2 + 0) * 1024 + ((l15 * 64 + lhi * 16) ^ sw);
    rbyte1 = (rw * 2 + 1) * 1024 + ((l15 * 64 + lhi * 16) ^ sw);
  }
  int wl15 = srow & 15;
  int wbyte = (srow >> 4) * 1024 + ((wl15 * 64 + sq * 16) ^ ((wl15 & 7) << 4));

#pragma unroll 1
  for (int chunk = rb; chunk < nchunk; chunk += NRB) {
    int grow = chunk * BMR + srow;
    if (grow > M - 1) grow = M - 1;
    const float* gsrc = mem + (size_t)grow * DD + sq * 8;
    float ssr = 0.f;

    float4 P0, P1, Q0, Q1, R0, R1, T0, T1;

    // ---- prologue: P=B0 (convert now), Q=B1, R=B2 in flight; T filled step 0
    P0 = *(const float4*)(gsrc);
    P1 = *(const float4*)(gsrc + 4);
    Q0 = *(const float4*)(gsrc + 32);
    Q1 = *(const float4*)(gsrc + 36);
    R0 = *(const float4*)(gsrc + 64);
    R1 = *(const float4*)(gsrc + 68);
    __builtin_amdgcn_sched_barrier(0);
    ssr += SQ8(P0, P1);
    {
      uint4 bw;
      PACK_BW(bw, P0, P1);
      *(uint4*)((char*)Bs[0] + wbyte) = bw;
    }
    asm volatile("s_waitcnt lgkmcnt(0)" ::: "memory");
    __builtin_amdgcn_sched_barrier(0);
    __builtin_amdgcn_s_barrier();

    f32x4 acc[9][2];
#pragma unroll
    for (int p = 0; p < 9; ++p) {
      f32x4 z = {0.f, 0.f, 0.f, 0.f};
      acc[p][0] = z;
      acc[p][1] = z;
    }

    // rotation (period 4): step n: convert set (n+1)%4, issue into set (n+3)%4
    // steady: steps 0..19 (issue guard n+3<24 true throughout)
#pragma unroll 1
    for (int n = 0; n < 20; n += 4) {
      KSTEP(n + 0, 0, Q0, Q1, T0, T1);
      KSTEP(n + 1, 1, R0, R1, P0, P1);
      KSTEP(n + 2, 0, T0, T1, Q0, Q1);
      KSTEP(n + 3, 1, P0, P1, R0, R1);
    }
    // tail: steps 20..23 (compile-time guards fold issue/convert)
    KSTEP(20, 0, Q0, Q1, T0, T1);
    KSTEP(21, 1, R0, R1, P0, P1);
    KSTEP(22, 0, T0, T1, Q0, Q1);
    KSTEP(23, 1, P0, P1, R0, R1);

    // ---- ssq: reduce over the 4 k-seg threads per row (in-wave) ----
    float s2 = ssr + __shfl_xor(ssr, 1, 64);
    s2 += __shfl_xor(s2, 2, 64);
    if (sq == 0) ssq[srow] = s2;
    __syncthreads();

    // ---- epilogue: dist + min over this chunk's 64 rows ----
    float inv0, inv1;
    bool ok0, ok1;
    {
      int rl0 = (rw * 2 + 0) * 16 + l15;
      int rl1 = (rw * 2 + 1) * 16 + l15;
      inv0 = 1.0f / (sqrtf(ssq[rl0]) + EPSF);
      inv1 = 1.0f / (sqrtf(ssq[rl1]) + EPSF);
      ok0 = (chunk * BMR + rl0) < M;
      ok1 = (chunk * BMR + rl1) < M;
    }
#pragma unroll
    for (int p = 0; p < 9; ++p) {
#pragma unroll
      for (int q = 0; q < 4; ++q) {
        float e0 = ok0 ? (1.0f - acc[p][0][q] * inv0) : 1e30f;
        float e1 = ok1 ? (1.0f - acc[p][1][q] * inv1) : 1e30f;
        float d = fminf(e0, e1);
        d = fminf(d, __shfl_xor(d, 1, 64));
        d = fminf(d, __shfl_xor(d, 2, 64));
        d = fminf(d, __shfl_xor(d, 4, 64));
        d = fminf(d, __shfl_xor(d, 8, 64));
        if (l15 == 0) {
          int pl = (pw * 9 + p) * 16 + lhi * 4 + q;
          smin[rw][pl] = fminf(smin[rw][pl], d);
        }
      }
    }
    __syncthreads();   // smin/ssq settled before next chunk
  }

  for (int i = t; i < 288; i += 256)
    partial[(size_t)rb * NPATCH + c * 288 + i] = fminf(smin[0][i], smin[1][i]);
}

// ---------------- kernel 4: min over partials -> patch_scores ----------------
__global__ __launch_bounds__(256) void k_colmin(const float* __restrict__ partial,
                                                float* __restrict__ out, int nb) {
  int p = blockIdx.x;   // 576
  int t = threadIdx.x;
  float v = 1e30f;
  for (int b = t; b < nb; b += 256) v = fminf(v, partial[(size_t)b * NPATCH + p]);
#pragma unroll
  for (int m = 1; m < 64; m <<= 1) v = fminf(v, __shfl_xor(v, m, 64));
  __shared__ float wmin[4];
  if ((t & 63) == 0) wmin[t >> 6] = v;
  __syncthreads();
  if (t == 0) out[p] = fminf(fminf(wmin[0], wmin[1]), fminf(wmin[2], wmin[3]));
}

// ---------------- kernel 5: top-k mean -> image score ----------------
__global__ __launch_bounds__(256) void k_topk(float* __restrict__ out,
                                              const int* __restrict__ topk_p) {
  __shared__ float vals[NPATCH];
  __shared__ float wv[4];
  __shared__ int wi[4];
  __shared__ float ssum;
  int t = threadIdx.x;
  for (int p = t; p < NPATCH; p += 256) vals[p] = out[p];
  if (t == 0) ssum = 0.f;
  int k = topk_p[0];
  if (k > NPATCH) k = NPATCH;
  if (k < 1) k = 1;
  __syncthreads();
  for (int it = 0; it < k; ++it) {
    float bv = -1e30f;
    int bi = 0;
    for (int p = t; p < NPATCH; p += 256) {
      float x = vals[p];
      if (x > bv) { bv = x; bi = p; }
    }
#pragma unroll
    for (int m = 1; m < 64; m <<= 1) {
      float ov = __shfl_xor(bv, m, 64);
      int oi = __shfl_xor(bi, m, 64);
      if (ov > bv || (ov == bv && oi < bi)) { bv = ov; bi = oi; }
    }
    if ((t & 63) == 0) { wv[t >> 6] = bv; wi[t >> 6] = bi; }
    __syncthreads();
    if (t == 0) {
      float fbv = wv[0]; int fbi = wi[0];
      for (int q = 1; q < 4; ++q)
        if (wv[q] > fbv || (wv[q] == fbv && wi[q] < fbi)) { fbv = wv[q]; fbi = wi[q]; }
      ssum += fbv;
      vals[fbi] = -1e30f;
    }
    __syncthreads();
  }
  if (t == 0) out[NPATCH] = ssum / (float)k;
}

extern "C" void kernel_launch(void* const* d_in, const int* in_sizes, int n_in,
                              void* d_out, int out_size, void* d_ws, size_t ws_size,
                              hipStream_t stream) {
  const float* pf = (const float*)d_in[0];
  const float* mem = (const float*)d_in[1];
  const int* topk = (const int*)d_in[2];
  float* out = (float*)d_out;
  int M = in_sizes[1] / DD;                      // 200000
  int nchunk = (M + BMR - 1) / BMR;              // 3125

  // ws layout: Fws (24*36*512 shorts = 884736B) | invn (576*4) | partial (384*576*4)
  unsigned short* Fws = (unsigned short*)d_ws;
  float* invn = (float*)((char*)d_ws + 884736);
  float* partial = (float*)((char*)d_ws + 884736 + 2304);

  k_norm<<<NPATCH, 256, 0, stream>>>(pf, invn);
  k_pack<<<864, 256, 0, stream>>>(pf, invn, Fws);
  k_main<<<2 * NRB, 256, 0, stream>>>(Fws, mem, partial, M, nchunk);
  k_colmin<<<NPATCH, 256, 0, stream>>>(partial, out, NRB);
  k_topk<<<1, 256, 0, stream>>>(out, topk);
}

// Round 10
// 421.379 us; speedup vs baseline: 8.1765x; 1.2015x over previous
//
#include <hip/hip_runtime.h>
#include <hip/hip_bf16.h>

#define DD 768
#define NPATCH 576
#define NPAD 640          // 40 patch tiles of 16
#define NPT 40
#define BMR 64            // mem rows per chunk
#define QF 192            // floats per quarter-chunk per row (6 k-slabs of 32)
#define GRID 256
#define EPSF 1e-6f

typedef short bf16x8 __attribute__((ext_vector_type(8)));
typedef float f32x4 __attribute__((ext_vector_type(4)));

__device__ __forceinline__ unsigned short f2bf(float x) {
  __hip_bfloat16 h = __float2bfloat16(x);
  return __builtin_bit_cast(unsigned short, h);
}

__device__ __forceinline__ void gload_lds16(const float* g, char* lds) {
  __builtin_amdgcn_global_load_lds(
      (const __attribute__((address_space(1))) unsigned int*)(g),
      (__attribute__((address_space(3))) unsigned int*)(lds), 16, 0, 0);
}

// ---------------- kernel 1: patch row norms ----------------
__global__ __launch_bounds__(256) void k_norm(const float* __restrict__ pf,
                                              float* __restrict__ invn) {
  int row = blockIdx.x;          // 576
  int t = threadIdx.x;
  const float* src = pf + (size_t)row * DD;
  float v0 = src[t], v1 = src[t + 256], v2 = src[t + 512];
  float ss = v0 * v0 + v1 * v1 + v2 * v2;
#pragma unroll
  for (int m = 1; m < 64; m <<= 1) ss += __shfl_xor(ss, m, 64);
  __shared__ float wss[4];
  if ((t & 63) == 0) wss[t >> 6] = ss;
  __syncthreads();
  if (t == 0) {
    float tot = wss[0] + wss[1] + wss[2] + wss[3];
    invn[row] = 1.0f / (sqrtf(tot) + EPSF);
  }
}

// ---------------- kernel 2: pack F into slab-fragment layout ----------------
// Fws[ks32][ptg][slot][8] bf16: patch = ptg*16+(slot&15), k = ks32*32+(slot>>4)*8+j
__global__ __launch_bounds__(256) void k_pack(const float* __restrict__ pf,
                                              const float* __restrict__ invn,
                                              unsigned short* __restrict__ Fws) {
  int bid = blockIdx.x;          // 960 = 24 ks * 40 ptg
  int ks = bid / NPT, ptg = bid % NPT;
  int t = threadIdx.x;
  int i = t * 2;                 // short index in region [0,512)
  int s = i >> 3, j = i & 7;
  int p = ptg * 16 + (s & 15);
  int k = ks * 32 + (s >> 4) * 8 + j;
  unsigned int outw = 0;
  if (p < NPATCH) {
    float sc = invn[p];
    float a0 = pf[(size_t)p * DD + k] * sc;
    float a1 = pf[(size_t)p * DD + k + 1] * sc;
    outw = (unsigned int)f2bf(a0) | ((unsigned int)f2bf(a1) << 16);
  }
  ((unsigned int*)Fws)[(size_t)bid * 256 + t] = outw;
}

#define PACK_BW(bw, u0, u1)                                               \
  bw.x = (unsigned int)f2bf(u0.x) | ((unsigned int)f2bf(u0.y) << 16);     \
  bw.y = (unsigned int)f2bf(u0.z) | ((unsigned int)f2bf(u0.w) << 16);     \
  bw.z = (unsigned int)f2bf(u1.x) | ((unsigned int)f2bf(u1.y) << 16);     \
  bw.w = (unsigned int)f2bf(u1.z) | ((unsigned int)f2bf(u1.w) << 16);

#define SQ8(u0, u1)                                                        \
  (u0.x * u0.x + u0.y * u0.y + u0.z * u0.z + u0.w * u0.w +                 \
   u1.x * u1.x + u1.y * u1.y + u1.z * u1.z + u1.w * u1.w)

// One k-slab step (s = 0..5 literal) within phase q (runtime):
//  - load 5 A-frags (L2-resident packed F)
//  - issue 1 of the 6 gload_lds staging the NEXT quarter (fire-and-forget)
//  - 4 row-tiles: 2 ds_read_b128 fp32 -> cvt to bf16 frag (+ssq) -> 5 MFMA each
#define STEP(s)                                                              \
  {                                                                          \
    const unsigned short* Ak_ = Abase + (size_t)(q6 + (s)) * (NPT * 512);    \
    bf16x8 a_[5];                                                            \
    _Pragma("unroll") for (int p = 0; p < 5; ++p)                            \
        a_[p] = *(const bf16x8*)(Ak_ + p * 512);                             \
    __builtin_amdgcn_sched_barrier(0);                                       \
    gload_lds16((const float*)(gsrc + sbyte[s]),                             \
                (char*)BsF + dstb + (s) * 8192 + w * 1024);                  \
    __builtin_amdgcn_sched_barrier(0);                                       \
    _Pragma("unroll") for (int rt = 0; rt < 4; ++rt) {                       \
      int o0_ = rt * 12288 + rb768 + ((((s) * 8 + lhi2) ^ sw8x) << 4);       \
      float4 f0_ = *(const float4*)(bp + o0_);                               \
      float4 f1_ = *(const float4*)(bp + (o0_ ^ 16));                        \
      ssr[rt] += SQ8(f0_, f1_);                                              \
      uint4 bw_;                                                             \
      PACK_BW(bw_, f0_, f1_);                                                \
      bf16x8 b_ = __builtin_bit_cast(bf16x8, bw_);                           \
      _Pragma("unroll") for (int p = 0; p < 5; ++p)                          \
        acc[p][rt] = __builtin_amdgcn_mfma_f32_16x16x32_bf16(a_[p], b_, acc[p][rt], 0, 0, 0); \
    }                                                                        \
    __builtin_amdgcn_sched_barrier(0);                                       \
  }

// ---------------- kernel 3: main MFMA kernel ----------------
// 512 threads = 8 waves; wave w owns patch-tiles w*5..w*5+4 x all 4 row-tiles.
// Each 64-row chunk is owned by exactly ONE block -> B read once from HBM.
// B staged fp32 via global_load_lds into 2x48KB quarter buffers (swizzled
// source, linear dest); one __syncthreads per 6-step phase.
__global__ __launch_bounds__(512, 2) void k_main(const unsigned short* __restrict__ Fws,
                                                 const float* __restrict__ mem,
                                                 float* __restrict__ partial,
                                                 int M, int nchunk) {
  __shared__ __align__(16) float BsF[2][12288];   // 2 x 48KB fp32 quarters
  __shared__ float ssq[BMR];
  __shared__ float smin[NPAD];

  int t = threadIdx.x;
  int w = t >> 6, l = t & 63, l15 = l & 15, lhi = l >> 4;
  int lhi2 = lhi * 2, sw8x = l15 & 7, rb768 = l15 * 768;

  // staging source byte-offsets (within a chunk-quarter), pre-swizzled:
  // dest slot idx = i*512 + t -> (row, slot); source reads slot^(row&7)
  int sbyte[6];
#pragma unroll
  for (int i = 0; i < 6; ++i) {
    int idx = i * 512 + t;
    int r = idx / 48, sl = idx - r * 48;
    sbyte[i] = r * 3072 + ((sl ^ (r & 7)) << 4);
  }

  const unsigned short* Abase =
      Fws + (size_t)(w * 5) * 512 + (size_t)(lhi * 16 + l15) * 8;

  for (int i = t; i < NPAD; i += 512) smin[i] = 1e30f;

  int chunk = blockIdx.x;
  // prologue: stage (chunk, quarter 0) into buf0
  {
    const char* g0 = (const char*)mem + (size_t)chunk * (BMR * DD * 4);
#pragma unroll
    for (int i = 0; i < 6; ++i)
      gload_lds16((const float*)(g0 + sbyte[i]), (char*)BsF + i * 8192 + w * 1024);
  }

#pragma unroll 1
  for (; chunk < nchunk; chunk += GRID) {
    f32x4 acc[5][4];
#pragma unroll
    for (int p = 0; p < 5; ++p)
#pragma unroll
      for (int rt = 0; rt < 4; ++rt) {
        f32x4 z = {0.f, 0.f, 0.f, 0.f};
        acc[p][rt] = z;
      }
    float ssr[4] = {0.f, 0.f, 0.f, 0.f};

#pragma unroll 1
    for (int q = 0; q < 4; ++q) {
      __syncthreads();   // stage(q) complete+visible; prior readers of dest buf done
      int qn = (q + 1) & 3;
      int chS = (q == 3) ? chunk + GRID : chunk;
      if (chS >= nchunk) chS = chunk;                 // dummy re-stage (never read)
      const char* gsrc = (const char*)mem +
          ((size_t)chS * (BMR * DD) + (size_t)qn * QF) * 4;
      int dstb = (qn & 1) * 49152;
      const char* bp = (const char*)BsF + (q & 1) * 49152;
      int q6 = q * 6;
      STEP(0) STEP(1) STEP(2) STEP(3) STEP(4) STEP(5)
    }

    // ---- ssq publish (every wave computed identical sums; wave 0 writes) ----
#pragma unroll
    for (int rt = 0; rt < 4; ++rt) {
      float v = ssr[rt];
      v += __shfl_xor(v, 16, 64);
      v += __shfl_xor(v, 32, 64);
      if (w == 0 && l < 16) ssq[rt * 16 + l15] = v;
    }
    __syncthreads();

    // ---- epilogue: dist + min over this chunk's 64 rows ----
    float inv_[4];
    bool okr[4];
#pragma unroll
    for (int rt = 0; rt < 4; ++rt) {
      inv_[rt] = 1.0f / (sqrtf(ssq[rt * 16 + l15]) + EPSF);
      okr[rt] = (chunk * BMR + rt * 16 + l15) < M;
    }
#pragma unroll
    for (int p = 0; p < 5; ++p) {
#pragma unroll
      for (int qq = 0; qq < 4; ++qq) {
        float d = okr[0] ? (1.0f - acc[p][0][qq] * inv_[0]) : 1e30f;
        d = fminf(d, okr[1] ? (1.0f - acc[p][1][qq] * inv_[1]) : 1e30f);
        d = fminf(d, okr[2] ? (1.0f - acc[p][2][qq] * inv_[2]) : 1e30f);
        d = fminf(d, okr[3] ? (1.0f - acc[p][3][qq] * inv_[3]) : 1e30f);
        d = fminf(d, __shfl_xor(d, 1, 64));
        d = fminf(d, __shfl_xor(d, 2, 64));
        d = fminf(d, __shfl_xor(d, 4, 64));
        d = fminf(d, __shfl_xor(d, 8, 64));
        if (l15 == 0) {
          int pl = (w * 5 + p) * 16 + lhi * 4 + qq;
          smin[pl] = fminf(smin[pl], d);
        }
      }
    }
    // next loop-top __syncthreads orders smin/ssq for the following chunk
  }

  __syncthreads();
  for (int i = t; i < NPATCH; i += 512)
    partial[(size_t)blockIdx.x * NPAD + i] = smin[i];
}

// ---------------- kernel 4: min over partials -> patch_scores ----------------
__global__ __launch_bounds__(256) void k_colmin(const float* __restrict__ partial,
                                                float* __restrict__ out, int nb) {
  int p = blockIdx.x;   // 576
  int t = threadIdx.x;
  float v = 1e30f;
  for (int b = t; b < nb; b += 256) v = fminf(v, partial[(size_t)b * NPAD + p]);
#pragma unroll
  for (int m = 1; m < 64; m <<= 1) v = fminf(v, __shfl_xor(v, m, 64));
  __shared__ float wmin[4];
  if ((t & 63) == 0) wmin[t >> 6] = v;
  __syncthreads();
  if (t == 0) out[p] = fminf(fminf(wmin[0], wmin[1]), fminf(wmin[2], wmin[3]));
}

// ---------------- kernel 5: top-k mean -> image score ----------------
__global__ __launch_bounds__(256) void k_topk(float* __restrict__ out,
                                              const int* __restrict__ topk_p) {
  __shared__ float vals[NPATCH];
  __shared__ float wv[4];
  __shared__ int wi[4];
  __shared__ float ssum;
  int t = threadIdx.x;
  for (int p = t; p < NPATCH; p += 256) vals[p] = out[p];
  if (t == 0) ssum = 0.f;
  int k = topk_p[0];
  if (k > NPATCH) k = NPATCH;
  if (k < 1) k = 1;
  __syncthreads();
  for (int it = 0; it < k; ++it) {
    float bv = -1e30f;
    int bi = 0;
    for (int p = t; p < NPATCH; p += 256) {
      float x = vals[p];
      if (x > bv) { bv = x; bi = p; }
    }
#pragma unroll
    for (int m = 1; m < 64; m <<= 1) {
      float ov = __shfl_xor(bv, m, 64);
      int oi = __shfl_xor(bi, m, 64);
      if (ov > bv || (ov == bv && oi < bi)) { bv = ov; bi = oi; }
    }
    if ((t & 63) == 0) { wv[t >> 6] = bv; wi[t >> 6] = bi; }
    __syncthreads();
    if (t == 0) {
      float fbv = wv[0]; int fbi = wi[0];
      for (int q = 1; q < 4; ++q)
        if (wv[q] > fbv || (wv[q] == fbv && wi[q] < fbi)) { fbv = wv[q]; fbi = wi[q]; }
      ssum += fbv;
      vals[fbi] = -1e30f;
    }
    __syncthreads();
  }
  if (t == 0) out[NPATCH] = ssum / (float)k;
}

extern "C" void kernel_launch(void* const* d_in, const int* in_sizes, int n_in,
                              void* d_out, int out_size, void* d_ws, size_t ws_size,
                              hipStream_t stream) {
  const float* pf = (const float*)d_in[0];
  const float* mem = (const float*)d_in[1];
  const int* topk = (const int*)d_in[2];
  float* out = (float*)d_out;
  int M = in_sizes[1] / DD;                      // 200000
  int nchunk = (M + BMR - 1) / BMR;              // 3125

  // ws: Fws (24*40*512 shorts = 983040B) | invn (2560B) | partial (256*640*4)
  unsigned short* Fws = (unsigned short*)d_ws;
  float* invn = (float*)((char*)d_ws + 983040);
  float* partial = (float*)((char*)d_ws + 983040 + 2560);

  int grid = GRID;
  if (grid > nchunk) grid = nchunk;

  k_norm<<<NPATCH, 256, 0, stream>>>(pf, invn);
  k_pack<<<24 * NPT, 256, 0, stream>>>(pf, invn, Fws);
  k_main<<<grid, 512, 0, stream>>>(Fws, mem, partial, M, nchunk);
  k_colmin<<<NPATCH, 256, 0, stream>>>(partial, out, grid);
  k_topk<<<1, 256, 0, stream>>>(out, topk);
}